// Round 9
// baseline (1345.548 us; speedup 1.0000x reference)
//
#include <hip/hip_runtime.h>
#include <hip/hip_bf16.h>
#include <stdint.h>

// Problem constants
#define B_ROWS 32768
#define KTOT   3584   // 1024 + 512 + 2048 (concat of stream features)
#define OUT_N  1024

typedef unsigned short ushort_t;
typedef __attribute__((ext_vector_type(8))) short bf16x8;
typedef __attribute__((ext_vector_type(4))) float f32x4;
typedef __attribute__((ext_vector_type(8))) unsigned short u16x8;

// stash geometry: row stride 136B (68 ushorts) -> conflict-free writes
#define STASH_ROW   136
#define STASH_SEG   (128 * STASH_ROW)   // 17408
#define STASH_BASE  98304

__device__ __forceinline__ float b2f(unsigned short u) {
    union { unsigned int i; float f; } x; x.i = ((unsigned int)u) << 16; return x.f;
}
__device__ __forceinline__ unsigned short f2b(float f) {
    union { float f; unsigned int i; } x; x.f = f;
    unsigned int r = x.i + 0x7fffu + ((x.i >> 16) & 1u);
    return (unsigned short)(r >> 16);
}

// async global->LDS, 16B per lane
__device__ __forceinline__ void gload_lds16(const void* g, void* l) {
    auto g1 = reinterpret_cast<const __attribute__((address_space(1))) char*>(
        reinterpret_cast<uintptr_t>(g));
    auto l3 = reinterpret_cast<__attribute__((address_space(3))) char*>(
        (uint32_t)reinterpret_cast<uintptr_t>(l));
    __builtin_amdgcn_global_load_lds(g1, l3, 16, 0, 0);
}

// ds_read_b128 with compile-time offset
template<int OFF>
__device__ __forceinline__ bf16x8 dsr(uint32_t addr) {
    bf16x8 d;
    asm volatile("ds_read_b128 %0, %1 offset:%2" : "=v"(d) : "v"(addr), "i"(OFF));
    return d;
}

// ---------------------------------------------------------------------------
// Kernel 1: weight pack. WT[n][k] (bf16, 4096 x 3584).
// ---------------------------------------------------------------------------
__global__ __launch_bounds__(256) void pack_wt_kernel(
    const float* __restrict__ Wa, const float* __restrict__ Wga,
    const float* __restrict__ Wb, const float* __restrict__ Wgb,
    const float* __restrict__ Wc, const float* __restrict__ Wgc,
    ushort_t* __restrict__ WT)
{
    int s = blockIdx.y;
    const float *Ws, *Wgs; int d, koff;
    if (s == 0)      { Ws = Wa; Wgs = Wga; d = 1024; koff = 0;    }
    else if (s == 1) { Ws = Wb; Wgs = Wgb; d = 512;  koff = 1024; }
    else             { Ws = Wc; Wgs = Wgc; d = 2048; koff = 1536; }
    int kt = blockIdx.x >> 6;
    int ntile = blockIdx.x & 63;
    if (kt >= (d >> 6)) return;
    int k0 = kt * 64, n0 = ntile * 64;
    const float* src; int ld, ncol0;
    if (n0 < 1024) { src = Ws;  ld = 1024; ncol0 = n0; }
    else           { src = Wgs; ld = 3072; ncol0 = n0 - 1024; }

    __shared__ float tile[64][65];
    int tx = threadIdx.x & 63, ty = threadIdx.x >> 6;
    for (int r = ty; r < 64; r += 4)
        tile[r][tx] = src[(size_t)(k0 + r) * ld + ncol0 + tx];
    __syncthreads();
    for (int r = ty; r < 64; r += 4)
        WT[(size_t)(n0 + r) * KTOT + koff + k0 + tx] = f2b(tile[tx][r]);
}

__global__ __launch_bounds__(256) void pack_bias_kernel(
    const float* __restrict__ ba, const float* __restrict__ bb, const float* __restrict__ bc,
    const float* __restrict__ bga, const float* __restrict__ bgb, const float* __restrict__ bgc,
    float* __restrict__ bias)
{
    int i = blockIdx.x * 256 + threadIdx.x;
    if (i >= 6144) return;
    float v;
    if (i < 1024)      v = ba[i];
    else if (i < 2048) v = bb[i - 1024];
    else if (i < 3072) v = bc[i - 2048];
    else { int g = i - 3072; v = bga[g] + bgb[g] + bgc[g]; }
    bias[i] = v;
}

// ---------------------------------------------------------------------------
// Kernel 2: LayerNorm + ReLU + cast to bf16, writes F[32768][3584]
// ---------------------------------------------------------------------------
__global__ __launch_bounds__(256) void ln_relu_kernel(
    const float* __restrict__ xa, const float* __restrict__ xb, const float* __restrict__ xc,
    const float* __restrict__ wa, const float* __restrict__ wb, const float* __restrict__ wc,
    const float* __restrict__ ba, const float* __restrict__ bb, const float* __restrict__ bc,
    ushort_t* __restrict__ F)
{
    int row = blockIdx.x;
    int s = blockIdx.y;
    const float *x, *w, *b; int d, koff;
    if (s == 0)      { x = xa; w = wa; b = ba; d = 1024; koff = 0;    }
    else if (s == 1) { x = xb; w = wb; b = bb; d = 512;  koff = 1024; }
    else             { x = xc; w = wc; b = bc; d = 2048; koff = 1536; }
    const float* xr = x + (size_t)row * d;
    int tid = threadIdx.x;

    float s1 = 0.f, s2 = 0.f;
    for (int i = tid * 4; i < d; i += 1024) {
        float4 v = *(const float4*)(xr + i);
        s1 += v.x + v.y + v.z + v.w;
        s2 += v.x * v.x + v.y * v.y + v.z * v.z + v.w * v.w;
    }
    for (int o = 32; o > 0; o >>= 1) {
        s1 += __shfl_down(s1, o, 64);
        s2 += __shfl_down(s2, o, 64);
    }
    __shared__ float red1[4], red2[4], bcast[2];
    int wv = tid >> 6, ln = tid & 63;
    if (ln == 0) { red1[wv] = s1; red2[wv] = s2; }
    __syncthreads();
    if (tid == 0) {
        float t1 = red1[0] + red1[1] + red1[2] + red1[3];
        float t2 = red2[0] + red2[1] + red2[2] + red2[3];
        float mean = t1 / d;
        float var = t2 / d - mean * mean;
        bcast[0] = mean;
        bcast[1] = rsqrtf(var + 1e-5f);
    }
    __syncthreads();
    float mean = bcast[0], rstd = bcast[1];

    ushort_t* Fr = F + (size_t)row * KTOT + koff;
    for (int i = tid * 4; i < d; i += 1024) {
        float4 v  = *(const float4*)(xr + i);
        float4 wv4 = *(const float4*)(w + i);
        float4 bv4 = *(const float4*)(b + i);
        float o0 = fmaxf(0.f, (v.x - mean) * rstd * wv4.x + bv4.x);
        float o1 = fmaxf(0.f, (v.y - mean) * rstd * wv4.y + bv4.y);
        float o2 = fmaxf(0.f, (v.z - mean) * rstd * wv4.z + bv4.z);
        float o3 = fmaxf(0.f, (v.w - mean) * rstd * wv4.w + bv4.w);
        union { ushort_t u[4]; uint2 v2; } pk;
        pk.u[0] = f2b(o0); pk.u[1] = f2b(o1); pk.u[2] = f2b(o2); pk.u[3] = f2b(o3);
        *(uint2*)(Fr + i) = pk.v2;
    }
}

// ---------------------------------------------------------------------------
// Kernel 3: FUSED GEMM + gate softmax + merge. No C buffer.
// Block = (rp, g): 128 rows x col-group g (64 cols of OUT_N).
// GRID NESTING (R9): g-OUTER, rp-INNER. XCD (bid&7) owns g = xcd for the
// first 256 blocks of its stripe, then g = 8+xcd. Its WT slice (4x64 rows x
// 7KB = 1.84MB) stays L2-resident for an entire 256-rp sweep; all 8 XCDs
// sweep rp in the same order so each F panel is L3-fetched once and shared.
// ---------------------------------------------------------------------------
__global__ __launch_bounds__(512, 1) void gemm_fused_kernel(
    const ushort_t* __restrict__ F, const ushort_t* __restrict__ WT,
    const float* __restrict__ bias, float* __restrict__ out)
{
    extern __shared__ char lds8[];
    uint32_t lds_base = (uint32_t)(uintptr_t)lds8;

    // ---- block decode: g-outer, rp-inner
    int bid = blockIdx.x;
    int xcd = bid & 7;
    int i   = bid >> 3;                       // 0..511
    int g   = (i < 256) ? xcd : 8 + xcd;      // col-group 0..15
    int rp  = (i < 256) ? i : i - 256;        // 0..255
    int row0 = rp * 128;

    int tid = threadIdx.x, w = tid >> 6, l = tid & 63;
    int mh = w >> 2;        // m-half (64 rows)
    int p  = w & 3;         // panel: 0=out, 1..3=gate
    int rl = l & 15, hi = l >> 4;

    // ---- staging sources (pre-swizzled: LDS linear dest == XOR-swz layout)
    int trow = tid >> 3;                                  // 0..63
    int scol = (((tid & 7) ^ (trow & 7)) << 3);           // swz elem col in [0,64)
    const ushort_t* FA = F  + (size_t)(row0 + trow) * KTOT + scol;
    const ushort_t* WB = WT + (size_t)(g * 64 + trow) * KTOT + scol;

#define STG(BUFOFF, kt) do {                                                      \
        gload_lds16(FA + (size_t)(kt) * 64,                                       \
                    (void*)(uintptr_t)(lds_base + (BUFOFF) + tid * 16u));         \
        gload_lds16(FA + (size_t)(kt) * 64 + 64 * KTOT,                           \
                    (void*)(uintptr_t)(lds_base + (BUFOFF) + 8192u + tid * 16u)); \
        _Pragma("unroll")                                                         \
        for (int q = 0; q < 4; ++q)                                               \
            gload_lds16(WB + (size_t)(kt) * 64 + (size_t)q * 1024 * KTOT,         \
                        (void*)(uintptr_t)(lds_base + (BUFOFF) + 16384u +         \
                                           q * 8192u + tid * 16u));               \
    } while (0)

    // ---- ds_read bases (swizzled): 16B-col = (ks*4 + hi) ^ (l&7)
    uint32_t aA0 = lds_base + (uint32_t)((mh * 64 + rl) * 128 + ((hi    ) ^ (l & 7)) * 16);
    uint32_t aA1 = lds_base + (uint32_t)((mh * 64 + rl) * 128 + ((hi + 4) ^ (l & 7)) * 16);
    uint32_t bB0 = lds_base + 16384u + (uint32_t)((p * 64 + rl) * 128 + ((hi    ) ^ (l & 7)) * 16);
    uint32_t bB1 = lds_base + 16384u + (uint32_t)((p * 64 + rl) * 128 + ((hi + 4) ^ (l & 7)) * 16);

#define MFMA16(AV, BV) do {                                                      \
        __builtin_amdgcn_s_setprio(1);                                           \
        _Pragma("unroll")                                                        \
        for (int mi = 0; mi < 4; ++mi)                                           \
            _Pragma("unroll")                                                    \
            for (int ni = 0; ni < 4; ++ni)                                       \
                acc[mi][ni] = __builtin_amdgcn_mfma_f32_16x16x32_bf16(           \
                    AV[mi], BV[ni], acc[mi][ni], 0, 0, 0);                       \
        __builtin_amdgcn_s_setprio(0);                                           \
    } while (0)

    f32x4 acc[4][4];
    #pragma unroll
    for (int mi = 0; mi < 4; ++mi)
        #pragma unroll
        for (int ni = 0; ni < 4; ++ni)
            acc[mi][ni] = (f32x4){0.f, 0.f, 0.f, 0.f};

    // stash: base STASH_BASE, row stride 136B (conflict-free writes)
    auto stash_write = [&](int seg, int bias_base) {
        #pragma unroll
        for (int ni = 0; ni < 4; ++ni) {
            int col = ni * 16 + rl;
            float bv = bias[bias_base + col];
            #pragma unroll
            for (int mi = 0; mi < 4; ++mi) {
                int rloc = mh * 64 + mi * 16 + hi * 4;
                #pragma unroll
                for (int r = 0; r < 4; ++r)
                    *(ushort_t*)(lds8 + STASH_BASE + seg * STASH_SEG +
                                 (rloc + r) * STASH_ROW + col * 2) =
                        f2b(acc[mi][ni][r] + bv);
            }
        }
        #pragma unroll
        for (int mi = 0; mi < 4; ++mi)
            #pragma unroll
            for (int ni = 0; ni < 4; ++ni)
                acc[mi][ni] = (f32x4){0.f, 0.f, 0.f, 0.f};
    };

    const int nkt = KTOT / 64;   // 56, uniform for all blocks

    // ---- prologue: stage T0 -> buf0, drain, barrier
    STG(0u, 0);
    asm volatile("s_waitcnt vmcnt(0)" ::: "memory");
    __builtin_amdgcn_s_barrier();

    for (int t = 0; t < nkt; ++t) {
        const uint32_t co  = (t & 1) ? 49152u : 0u;
        const uint32_t no_ = co ^ 49152u;

        if (t + 1 < nkt) STG(no_, t + 1);     // next tile -> other buffer

        bf16x8 a0[4], a1[4], b0[4], b1[4];
        a0[0] = dsr<0>(aA0 + co); a0[1] = dsr<2048>(aA0 + co);
        a0[2] = dsr<4096>(aA0 + co); a0[3] = dsr<6144>(aA0 + co);
        b0[0] = dsr<0>(bB0 + co); b0[1] = dsr<2048>(bB0 + co);
        b0[2] = dsr<4096>(bB0 + co); b0[3] = dsr<6144>(bB0 + co);
        a1[0] = dsr<0>(aA1 + co); a1[1] = dsr<2048>(aA1 + co);
        a1[2] = dsr<4096>(aA1 + co); a1[3] = dsr<6144>(aA1 + co);
        b1[0] = dsr<0>(bB1 + co); b1[1] = dsr<2048>(bB1 + co);
        b1[2] = dsr<4096>(bB1 + co); b1[3] = dsr<6144>(bB1 + co);

        asm volatile("s_waitcnt lgkmcnt(8)" ::: "memory");   // a0+b0 landed
        __builtin_amdgcn_sched_barrier(0);
        MFMA16(a0, b0);
        asm volatile("s_waitcnt lgkmcnt(0)" ::: "memory");
        __builtin_amdgcn_sched_barrier(0);
        MFMA16(a1, b1);

        // k-segment flush for the out panel (waves with p==0)
        if (p == 0) {
            if (t == 15)      stash_write(0, g * 64);          // out_a
            else if (t == 23) stash_write(1, 1024 + g * 64);   // out_b
        }

        asm volatile("s_waitcnt vmcnt(0)" ::: "memory");   // T(t+1) landed
        __builtin_amdgcn_s_barrier();
    }
#undef STG
#undef MFMA16

    // ---- epilogue part 1: dump final accs to LDS
    if (p == 0) {
        stash_write(2, 2048 + g * 64);                     // out_c
    } else {
        // gate panel p-1 -> gates region (reuse staging area, base 0)
        int gi = p - 1;
        int bias_base = 3072 + gi * 1024 + g * 64;
        #pragma unroll
        for (int ni = 0; ni < 4; ++ni) {
            int col = ni * 16 + rl;
            float bv = bias[bias_base + col];
            #pragma unroll
            for (int mi = 0; mi < 4; ++mi) {
                int rloc = mh * 64 + mi * 16 + hi * 4;
                #pragma unroll
                for (int r = 0; r < 4; ++r)
                    *(ushort_t*)(lds8 + gi * STASH_SEG + (rloc + r) * STASH_ROW + col * 2) =
                        f2b(acc[mi][ni][r] + bv);
            }
        }
    }
    __syncthreads();

    // ---- epilogue part 2: softmax over gates + weighted merge -> fp32 out
    {
        int r  = tid >> 2;          // 0..127
        int cb = (tid & 3) * 16;    // col base within the 64-col group
        const char* rowp = lds8 + r * STASH_ROW + cb * 2;
        u16x8 g0a = *(const u16x8*)(rowp);
        u16x8 g0b = *(const u16x8*)(rowp + 16);
        u16x8 g1a = *(const u16x8*)(rowp + STASH_SEG);
        u16x8 g1b = *(const u16x8*)(rowp + STASH_SEG + 16);
        u16x8 g2a = *(const u16x8*)(rowp + 2 * STASH_SEG);
        u16x8 g2b = *(const u16x8*)(rowp + 2 * STASH_SEG + 16);
        u16x8 oaa = *(const u16x8*)(rowp + STASH_BASE);
        u16x8 oab = *(const u16x8*)(rowp + STASH_BASE + 16);
        u16x8 oba = *(const u16x8*)(rowp + STASH_BASE + STASH_SEG);
        u16x8 obb = *(const u16x8*)(rowp + STASH_BASE + STASH_SEG + 16);
        u16x8 oca = *(const u16x8*)(rowp + STASH_BASE + 2 * STASH_SEG);
        u16x8 ocb = *(const u16x8*)(rowp + STASH_BASE + 2 * STASH_SEG + 16);

        float res[16];
        #pragma unroll
        for (int k = 0; k < 8; ++k) {
            float a0 = b2f(g0a[k]), a1 = b2f(g1a[k]), a2 = b2f(g2a[k]);
            float m = fmaxf(a0, fmaxf(a1, a2));
            float e0 = __expf(a0 - m), e1 = __expf(a1 - m), e2 = __expf(a2 - m);
            float inv = 1.f / (e0 + e1 + e2);
            res[k] = (e0 * b2f(oaa[k]) + e1 * b2f(oba[k]) + e2 * b2f(oca[k])) * inv;
        }
        #pragma unroll
        for (int k = 0; k < 8; ++k) {
            float a0 = b2f(g0b[k]), a1 = b2f(g1b[k]), a2 = b2f(g2b[k]);
            float m = fmaxf(a0, fmaxf(a1, a2));
            float e0 = __expf(a0 - m), e1 = __expf(a1 - m), e2 = __expf(a2 - m);
            float inv = 1.f / (e0 + e1 + e2);
            res[8 + k] = (e0 * b2f(oab[k]) + e1 * b2f(obb[k]) + e2 * b2f(ocb[k])) * inv;
        }
        float* op = out + (size_t)(row0 + r) * OUT_N + g * 64 + cb;
        #pragma unroll
        for (int q = 0; q < 4; ++q) {
            f32x4 v = {res[q * 4 + 0], res[q * 4 + 1], res[q * 4 + 2], res[q * 4 + 3]};
            *(f32x4*)(op + q * 4) = v;
        }
    }
}

// ---------------------------------------------------------------------------
extern "C" void kernel_launch(void* const* d_in, const int* in_sizes, int n_in,
                              void* d_out, int out_size, void* d_ws, size_t ws_size,
                              hipStream_t stream)
{
    const float* x_a   = (const float*)d_in[0];
    const float* lnw_a = (const float*)d_in[1];
    const float* lnb_a = (const float*)d_in[2];
    const float* W_a   = (const float*)d_in[3];
    const float* b_a   = (const float*)d_in[4];
    const float* Wg_a  = (const float*)d_in[5];
    const float* bg_a  = (const float*)d_in[6];
    const float* x_b   = (const float*)d_in[7];
    const float* lnw_b = (const float*)d_in[8];
    const float* lnb_b = (const float*)d_in[9];
    const float* W_b   = (const float*)d_in[10];
    const float* b_b   = (const float*)d_in[11];
    const float* Wg_b  = (const float*)d_in[12];
    const float* bg_b  = (const float*)d_in[13];
    const float* x_c   = (const float*)d_in[14];
    const float* lnw_c = (const float*)d_in[15];
    const float* lnb_c = (const float*)d_in[16];
    const float* W_c   = (const float*)d_in[17];
    const float* b_c   = (const float*)d_in[18];
    const float* Wg_c  = (const float*)d_in[19];
    const float* bg_c  = (const float*)d_in[20];

    // Workspace: F (235MB) + WT (28MB) + bias
    char* ws = (char*)d_ws;
    ushort_t* F    = (ushort_t*)ws;                         // 32768*3584*2
    ushort_t* WT   = (ushort_t*)(ws + 234881024);           // 4096*3584*2
    float*    bias = (float*)   (ws + 234881024 + 29360128);// 6144*4

    hipLaunchKernelGGL(pack_wt_kernel, dim3(2048, 3), dim3(256), 0, stream,
                       W_a, Wg_a, W_b, Wg_b, W_c, Wg_c, WT);
    hipLaunchKernelGGL(pack_bias_kernel, dim3(24), dim3(256), 0, stream,
                       b_a, b_b, b_c, bg_a, bg_b, bg_c, bias);
    hipLaunchKernelGGL(ln_relu_kernel, dim3(32768, 3), dim3(256), 0, stream,
                       x_a, x_b, x_c, lnw_a, lnw_b, lnw_c, lnb_a, lnb_b, lnb_c, F);
    hipLaunchKernelGGL(gemm_fused_kernel, dim3(4096), dim3(512), 153600, stream,
                       F, WT, bias, (float*)d_out);
}

// Round 11
// 1160.354 us; speedup vs baseline: 1.1596x; 1.1596x over previous
//
#include <hip/hip_runtime.h>
#include <hip/hip_bf16.h>
#include <stdint.h>

// Problem constants
#define B_ROWS 32768
#define KTOT   3584   // 1024 + 512 + 2048 (concat of stream features)
#define OUT_N  1024

typedef unsigned short ushort_t;
typedef unsigned int   uint_t;
typedef __attribute__((ext_vector_type(8))) short bf16x8;
typedef __attribute__((ext_vector_type(4))) float f32x4;

__device__ __forceinline__ float b2f(unsigned short u) {
    union { unsigned int i; float f; } x; x.i = ((unsigned int)u) << 16; return x.f;
}
__device__ __forceinline__ unsigned short f2b(float f) {
    union { float f; unsigned int i; } x; x.f = f;
    unsigned int r = x.i + 0x7fffu + ((x.i >> 16) & 1u);
    return (unsigned short)(r >> 16);
}

// async global->LDS, 16B per lane
__device__ __forceinline__ void gload_lds16(const void* g, void* l) {
    auto g1 = reinterpret_cast<const __attribute__((address_space(1))) char*>(
        reinterpret_cast<uintptr_t>(g));
    auto l3 = reinterpret_cast<__attribute__((address_space(3))) char*>(
        (uint32_t)reinterpret_cast<uintptr_t>(l));
    __builtin_amdgcn_global_load_lds(g1, l3, 16, 0, 0);
}

// ds_read_b128 with compile-time offset
template<int OFF>
__device__ __forceinline__ bf16x8 dsr(uint32_t addr) {
    bf16x8 d;
    asm volatile("ds_read_b128 %0, %1 offset:%2" : "=v"(d) : "v"(addr), "i"(OFF));
    return d;
}

// ---------------------------------------------------------------------------
// Kernel 1: weight pack. WT[n][k] (bf16, 4096 x 3584).
// rows [0,1024): W columns; rows [1024,4096): Wg columns (row-1024 = gate col)
// k segmented a|b|c for both.
// ---------------------------------------------------------------------------
__global__ __launch_bounds__(256) void pack_wt_kernel(
    const float* __restrict__ Wa, const float* __restrict__ Wga,
    const float* __restrict__ Wb, const float* __restrict__ Wgb,
    const float* __restrict__ Wc, const float* __restrict__ Wgc,
    ushort_t* __restrict__ WT)
{
    int s = blockIdx.y;
    const float *Ws, *Wgs; int d, koff;
    if (s == 0)      { Ws = Wa; Wgs = Wga; d = 1024; koff = 0;    }
    else if (s == 1) { Ws = Wb; Wgs = Wgb; d = 512;  koff = 1024; }
    else             { Ws = Wc; Wgs = Wgc; d = 2048; koff = 1536; }
    int kt = blockIdx.x >> 6;
    int ntile = blockIdx.x & 63;
    if (kt >= (d >> 6)) return;
    int k0 = kt * 64, n0 = ntile * 64;
    const float* src; int ld, ncol0;
    if (n0 < 1024) { src = Ws;  ld = 1024; ncol0 = n0; }
    else           { src = Wgs; ld = 3072; ncol0 = n0 - 1024; }

    __shared__ float tile[64][65];
    int tx = threadIdx.x & 63, ty = threadIdx.x >> 6;
    for (int r = ty; r < 64; r += 4)
        tile[r][tx] = src[(size_t)(k0 + r) * ld + ncol0 + tx];
    __syncthreads();
    for (int r = ty; r < 64; r += 4)
        WT[(size_t)(n0 + r) * KTOT + koff + k0 + tx] = f2b(tile[tx][r]);
}

__global__ __launch_bounds__(256) void pack_bias_kernel(
    const float* __restrict__ ba, const float* __restrict__ bb, const float* __restrict__ bc,
    const float* __restrict__ bga, const float* __restrict__ bgb, const float* __restrict__ bgc,
    float* __restrict__ bias)
{
    int i = blockIdx.x * 256 + threadIdx.x;
    if (i >= 6144) return;
    float v;
    if (i < 1024)      v = ba[i];
    else if (i < 2048) v = bb[i - 1024];
    else if (i < 3072) v = bc[i - 2048];
    else { int g = i - 3072; v = bga[g] + bgb[g] + bgc[g]; }
    bias[i] = v;
}

// ---------------------------------------------------------------------------
// Kernel 2: LayerNorm + ReLU + cast to bf16, writes F[32768][3584]
// ---------------------------------------------------------------------------
__global__ __launch_bounds__(256) void ln_relu_kernel(
    const float* __restrict__ xa, const float* __restrict__ xb, const float* __restrict__ xc,
    const float* __restrict__ wa, const float* __restrict__ wb, const float* __restrict__ wc,
    const float* __restrict__ ba, const float* __restrict__ bb, const float* __restrict__ bc,
    ushort_t* __restrict__ F)
{
    int row = blockIdx.x;
    int s = blockIdx.y;
    const float *x, *w, *b; int d, koff;
    if (s == 0)      { x = xa; w = wa; b = ba; d = 1024; koff = 0;    }
    else if (s == 1) { x = xb; w = wb; b = bb; d = 512;  koff = 1024; }
    else             { x = xc; w = wc; b = bc; d = 2048; koff = 1536; }
    const float* xr = x + (size_t)row * d;
    int tid = threadIdx.x;

    float s1 = 0.f, s2 = 0.f;
    for (int i = tid * 4; i < d; i += 1024) {
        float4 v = *(const float4*)(xr + i);
        s1 += v.x + v.y + v.z + v.w;
        s2 += v.x * v.x + v.y * v.y + v.z * v.z + v.w * v.w;
    }
    for (int o = 32; o > 0; o >>= 1) {
        s1 += __shfl_down(s1, o, 64);
        s2 += __shfl_down(s2, o, 64);
    }
    __shared__ float red1[4], red2[4], bcast[2];
    int wv = tid >> 6, ln = tid & 63;
    if (ln == 0) { red1[wv] = s1; red2[wv] = s2; }
    __syncthreads();
    if (tid == 0) {
        float t1 = red1[0] + red1[1] + red1[2] + red1[3];
        float t2 = red2[0] + red2[1] + red2[2] + red2[3];
        float mean = t1 / d;
        float var = t2 / d - mean * mean;
        bcast[0] = mean;
        bcast[1] = rsqrtf(var + 1e-5f);
    }
    __syncthreads();
    float mean = bcast[0], rstd = bcast[1];

    ushort_t* Fr = F + (size_t)row * KTOT + koff;
    for (int i = tid * 4; i < d; i += 1024) {
        float4 v  = *(const float4*)(xr + i);
        float4 wv4 = *(const float4*)(w + i);
        float4 bv4 = *(const float4*)(b + i);
        float o0 = fmaxf(0.f, (v.x - mean) * rstd * wv4.x + bv4.x);
        float o1 = fmaxf(0.f, (v.y - mean) * rstd * wv4.y + bv4.y);
        float o2 = fmaxf(0.f, (v.z - mean) * rstd * wv4.z + bv4.z);
        float o3 = fmaxf(0.f, (v.w - mean) * rstd * wv4.w + bv4.w);
        union { ushort_t u[4]; uint2 v2; } pk;
        pk.u[0] = f2b(o0); pk.u[1] = f2b(o1); pk.u[2] = f2b(o2); pk.u[3] = f2b(o3);
        *(uint2*)(Fr + i) = pk.v2;
    }
}

// ---------------------------------------------------------------------------
// Kernel 3: FUSED GEMM + softmax-merge, thread-local (no LDS stash).
// Block = (rp, gp): 128 rows x col-groups {gp, gp+8}. 8 B-panels of 64 WT
// rows: pp = 2*section + h, WTrow = (pp>>1)*1024 + (gp+8*(pp&1))*64 + wrow.
// acc[h][sec][mi] f32x4; out_a/out_b flushed to packed bf16 regs at t=31/47
// of 112 BK=32 tiles; merge fully in registers; fp32 d_out direct.
//
// SYNC (R10 NaN fix): per tile {vmcnt(5) -> s_barrier -> STG(t+2, ring) ->
// ds_read(t) -> lgkm(4)+MFMA -> lgkm(0)+MFMA}. vmcnt BEFORE the barrier makes
// every wave's tile-t staging visible block-wide; STG after the barrier is
// safe because each wave's lgkmcnt(0) (tile t-1) retired its reads of the
// ring target before reaching the barrier. 3-buffer ring -> 2-tile flight,
// counted waits only (never drains in steady state).
//
// Grid 2048 = 8 XCD x 32 rp x 8 gp, gp-inner: F panel (896KB) reused 8x
// back-to-back within an XCD (L2-resident); WT (28MB) hot chip-wide -> L3.
// LDS: 3 x (A 8KB + B 32KB) = 120KB.
// ---------------------------------------------------------------------------
__global__ __launch_bounds__(512, 1) void gemm_fused_kernel(
    const ushort_t* __restrict__ F, const ushort_t* __restrict__ WT,
    const float* __restrict__ bias, float* __restrict__ out)
{
    extern __shared__ char lds8[];
    uint32_t lds_base = (uint32_t)(uintptr_t)lds8;

    int bid = blockIdx.x;
    int xcd = bid & 7;
    int idx = bid >> 3;               // 0..255
    int rp  = xcd * 32 + (idx >> 3);  // 0..255 (XCD owns 32 contiguous rps)
    int gp  = idx & 7;                // g-pair: col-groups gp and gp+8
    int row0 = rp * 128;

    int tid = threadIdx.x, w = tid >> 6, l = tid & 63;
    int mh = w >> 2;              // 64-row half
    int nw = w & 3;               // 16-col group within 64
    int rl15 = l & 15, s0 = l >> 4;

    // ---- staging sources (pre-swizzled: slot^((row>>1)&3))
    int arow = tid >> 2;                                  // 0..127
    int scol = (((tid & 3) ^ ((tid >> 3) & 3)) << 3);     // element offset in K-window
    const ushort_t* Ag = F + (size_t)(row0 + arow) * KTOT + scol;
    int wrow = (tid >> 2) & 63;
    int e = tid >> 8;                                     // 0 or 1 (= h of staged panels)
    const ushort_t* Bg0 = WT + (size_t)((((e + 0) >> 1) * 1024) + (gp + 8 * ((e + 0) & 1)) * 64 + wrow) * KTOT + scol;
    const ushort_t* Bg1 = WT + (size_t)((((e + 2) >> 1) * 1024) + (gp + 8 * ((e + 2) & 1)) * 64 + wrow) * KTOT + scol;
    const ushort_t* Bg2 = WT + (size_t)((((e + 4) >> 1) * 1024) + (gp + 8 * ((e + 4) & 1)) * 64 + wrow) * KTOT + scol;
    const ushort_t* Bg3 = WT + (size_t)((((e + 6) >> 1) * 1024) + (gp + 8 * ((e + 6) & 1)) * 64 + wrow) * KTOT + scol;

#define STG(BUFOFF, kt) do {                                                          \
        gload_lds16(Ag  + (size_t)(kt) * 32,                                          \
                    (void*)(uintptr_t)(lds_base + (BUFOFF) + tid * 16u));             \
        gload_lds16(Bg0 + (size_t)(kt) * 32,                                          \
                    (void*)(uintptr_t)(lds_base + (BUFOFF) + 8192u + tid * 16u));     \
        gload_lds16(Bg1 + (size_t)(kt) * 32,                                          \
                    (void*)(uintptr_t)(lds_base + (BUFOFF) + 8192u + (tid + 512) * 16u)); \
        gload_lds16(Bg2 + (size_t)(kt) * 32,                                          \
                    (void*)(uintptr_t)(lds_base + (BUFOFF) + 8192u + (tid + 1024) * 16u)); \
        gload_lds16(Bg3 + (size_t)(kt) * 32,                                          \
                    (void*)(uintptr_t)(lds_base + (BUFOFF) + 8192u + (tid + 1536) * 16u)); \
    } while (0)

    // ---- ds_read bases (swizzled): slot = s0 ^ ((row>>1)&3)
    int fr = (rl15 >> 1) & 3;
    uint32_t aA = lds_base + (uint32_t)((mh * 64 + rl15) * 64 + ((s0 ^ fr) * 16));
    uint32_t bB = lds_base + 8192u + (uint32_t)((nw * 16 + rl15) * 64 + ((s0 ^ fr) * 16));

    f32x4 acc[2][4][4];   // [h][section: 0=out,1..3=gates][mi]
    #pragma unroll
    for (int h = 0; h < 2; ++h)
        #pragma unroll
        for (int j = 0; j < 4; ++j)
            #pragma unroll
            for (int mi = 0; mi < 4; ++mi)
                acc[h][j][mi] = (f32x4){0.f, 0.f, 0.f, 0.f};

    uint_t outa[2][8], outb[2][8];

    auto flush_seg = [&](uint_t (*dst)[8], int segbase) {
        #pragma unroll
        for (int h = 0; h < 2; ++h) {
            float bv = bias[segbase + (gp + 8 * h) * 64 + nw * 16 + rl15];
            #pragma unroll
            for (int mi = 0; mi < 4; ++mi)
                #pragma unroll
                for (int rr = 0; rr < 2; ++rr) {
                    uint_t u0 = f2b(acc[h][0][mi][rr * 2]     + bv);
                    uint_t u1 = f2b(acc[h][0][mi][rr * 2 + 1] + bv);
                    dst[h][mi * 2 + rr] = u0 | (u1 << 16);
                }
            #pragma unroll
            for (int mi = 0; mi < 4; ++mi)
                acc[h][0][mi] = (f32x4){0.f, 0.f, 0.f, 0.f};
        }
    };

    const int nkt = KTOT / 32;   // 112 BK=32 tiles

    // ---- prologue: T0 -> buf0, T1 -> buf1 (ring bufs at 0 / 40960 / 81920)
    STG(0u, 0);
    STG(40960u, 1);
    uint32_t co = 0u, st = 81920u;

    for (int t = 0; t < nkt; ++t) {
        int t2 = (t + 2 < nkt) ? t + 2 : nkt - 1;   // tail restage: harmless

        // my tile-t loads landed (only T(t+1)'s 5 remain outstanding)...
        asm volatile("s_waitcnt vmcnt(5)" ::: "memory");
        // ...then barrier: ALL waves' tile-t staging visible; all waves'
        // t-1 reads retired (their lgkmcnt(0) preceded barrier arrival).
        __builtin_amdgcn_s_barrier();
        // stage T(t+2) into the buffer read at t-1 (ring: (t+2)%3 == (t-1)%3)
        STG(st, t2);

        bf16x8 a[4], b0h[4], b1h[4];
        a[0] = dsr<0>(aA + co);     a[1] = dsr<1024>(aA + co);
        a[2] = dsr<2048>(aA + co);  a[3] = dsr<3072>(aA + co);
        // h0 panels: pp = 2j -> offset j*8192
        b0h[0] = dsr<0>(bB + co);      b0h[1] = dsr<8192>(bB + co);
        b0h[2] = dsr<16384>(bB + co);  b0h[3] = dsr<24576>(bB + co);
        // h1 panels: pp = 2j+1 -> offset j*8192 + 4096
        b1h[0] = dsr<4096>(bB + co);   b1h[1] = dsr<12288>(bB + co);
        b1h[2] = dsr<20480>(bB + co);  b1h[3] = dsr<28672>(bB + co);

        asm volatile("s_waitcnt lgkmcnt(4)" ::: "memory");  // a + b0h landed
        __builtin_amdgcn_sched_barrier(0);
        __builtin_amdgcn_s_setprio(1);
        #pragma unroll
        for (int j = 0; j < 4; ++j)
            #pragma unroll
            for (int mi = 0; mi < 4; ++mi)
                acc[0][j][mi] = __builtin_amdgcn_mfma_f32_16x16x32_bf16(
                    a[mi], b0h[j], acc[0][j][mi], 0, 0, 0);
        __builtin_amdgcn_s_setprio(0);
        asm volatile("s_waitcnt lgkmcnt(0)" ::: "memory");  // b1h landed
        __builtin_amdgcn_sched_barrier(0);
        __builtin_amdgcn_s_setprio(1);
        #pragma unroll
        for (int j = 0; j < 4; ++j)
            #pragma unroll
            for (int mi = 0; mi < 4; ++mi)
                acc[1][j][mi] = __builtin_amdgcn_mfma_f32_16x16x32_bf16(
                    a[mi], b1h[j], acc[1][j][mi], 0, 0, 0);
        __builtin_amdgcn_s_setprio(0);

        if (t == 31)      flush_seg(outa, 0);      // out_a: k [0,1024)
        else if (t == 47) flush_seg(outb, 1024);   // out_b: k [1024,1536)

        co = (co == 81920u) ? 0u : co + 40960u;
        st = (st == 81920u) ? 0u : st + 40960u;
    }
#undef STG

    // ---- epilogue: thread-local softmax merge -> fp32 out
    #pragma unroll
    for (int h = 0; h < 2; ++h) {
        int colg = (gp + 8 * h) * 64 + nw * 16 + rl15;
        float bc_ = bias[2048 + colg];
        float bg0 = bias[3072 + colg];
        float bg1 = bias[4096 + colg];
        float bg2 = bias[5120 + colg];
        #pragma unroll
        for (int mi = 0; mi < 4; ++mi) {
            #pragma unroll
            for (int r = 0; r < 4; ++r) {
                float oa = b2f((unsigned short)((outa[h][mi * 2 + (r >> 1)] >> ((r & 1) * 16)) & 0xffffu));
                float ob = b2f((unsigned short)((outb[h][mi * 2 + (r >> 1)] >> ((r & 1) * 16)) & 0xffffu));
                float oc = acc[h][0][mi][r] + bc_;
                float a0 = acc[h][1][mi][r] + bg0;
                float a1 = acc[h][2][mi][r] + bg1;
                float a2 = acc[h][3][mi][r] + bg2;
                float m  = fmaxf(a0, fmaxf(a1, a2));
                float e0 = __expf(a0 - m), e1 = __expf(a1 - m), e2 = __expf(a2 - m);
                float res = (e0 * oa + e1 * ob + e2 * oc) / (e0 + e1 + e2);
                out[(size_t)(row0 + mh * 64 + mi * 16 + s0 * 4 + r) * OUT_N + colg] = res;
            }
        }
    }
}

// ---------------------------------------------------------------------------
extern "C" void kernel_launch(void* const* d_in, const int* in_sizes, int n_in,
                              void* d_out, int out_size, void* d_ws, size_t ws_size,
                              hipStream_t stream)
{
    const float* x_a   = (const float*)d_in[0];
    const float* lnw_a = (const float*)d_in[1];
    const float* lnb_a = (const float*)d_in[2];
    const float* W_a   = (const float*)d_in[3];
    const float* b_a   = (const float*)d_in[4];
    const float* Wg_a  = (const float*)d_in[5];
    const float* bg_a  = (const float*)d_in[6];
    const float* x_b   = (const float*)d_in[7];
    const float* lnw_b = (const float*)d_in[8];
    const float* lnb_b = (const float*)d_in[9];
    const float* W_b   = (const float*)d_in[10];
    const float* b_b   = (const float*)d_in[11];
    const float* Wg_b  = (const float*)d_in[12];
    const float* bg_b  = (const float*)d_in[13];
    const float* x_c   = (const float*)d_in[14];
    const float* lnw_c = (const float*)d_in[15];
    const float* lnb_c = (const float*)d_in[16];
    const float* W_c   = (const float*)d_in[17];
    const float* b_c   = (const float*)d_in[18];
    const float* Wg_c  = (const float*)d_in[19];
    const float* bg_c  = (const float*)d_in[20];

    // Workspace: F (235MB) + WT (28MB) + bias
    char* ws = (char*)d_ws;
    ushort_t* F    = (ushort_t*)ws;                          // 32768*3584*2
    ushort_t* WT   = (ushort_t*)(ws + 234881024);            // 4096*3584*2
    float*    bias = (float*)   (ws + 234881024 + 29360128); // 6144*4

    hipLaunchKernelGGL(pack_wt_kernel, dim3(2048, 3), dim3(256), 0, stream,
                       W_a, Wg_a, W_b, Wg_b, W_c, Wg_c, WT);
    hipLaunchKernelGGL(pack_bias_kernel, dim3(24), dim3(256), 0, stream,
                       b_a, b_b, b_c, bg_a, bg_b, bg_c, bias);
    hipLaunchKernelGGL(ln_relu_kernel, dim3(32768, 3), dim3(256), 0, stream,
                       x_a, x_b, x_c, lnw_a, lnw_b, lnw_c, lnb_a, lnb_b, lnb_c, F);
    hipLaunchKernelGGL(gemm_fused_kernel, dim3(2048), dim3(512), 122880, stream,
                       F, WT, bias, (float*)d_out);
}